// Round 2
// baseline (241.755 us; speedup 1.0000x reference)
//
#include <hip/hip_runtime.h>

#define BB 16      // batch
#define SS 48      // seq len
#define VV 16000   // vocab
#define DD 128     // embed
#define NV 4       // vocab rows per thread in logits kernel

constexpr float EPS   = 1e-8f;
constexpr float SCALE = 10.0f;

// Kernel 1: per-batch causal prefix context, normalized.
// One block = one batch element, 64 threads (lane owns d=lane and d=lane+64).
// ctx_n layout: [S][B][D] so kernel 2 reads an 8 KB contiguous slice per s.
__global__ __launch_bounds__(64) void ctx_kernel(
    const int*   __restrict__ tokens,   // [B,S]
    const float* __restrict__ scalars,  // [S,V]
    const float* __restrict__ wvecs,    // [S,V,D]
    float*       __restrict__ ctx_n)    // [S,B,D]
{
    const int b    = blockIdx.x;
    const int lane = threadIdx.x;  // 0..63

    float a[SS], w0[SS], w1[SS];
    #pragma unroll
    for (int s = 0; s < SS; ++s) {
        const int tok = tokens[b * SS + s];                  // uniform -> SGPR
        a[s] = scalars[(size_t)s * VV + tok];                // uniform
        const float* wp = wvecs + ((size_t)s * VV + tok) * DD;
        w0[s] = wp[lane];
        w1[s] = wp[lane + 64];
    }

    float run0 = 0.f, run1 = 0.f;
    #pragma unroll
    for (int s = 0; s < SS; ++s) {
        // ||run|| over 128 d's: 2 partial squares/lane, butterfly over 64 lanes
        float p = fmaf(run0, run0, run1 * run1);
        #pragma unroll
        for (int off = 32; off > 0; off >>= 1)
            p += __shfl_xor(p, off);
        const float denom = fmaxf(sqrtf(p), EPS);  // torch F.normalize semantics
        float* o = ctx_n + ((size_t)s * BB + b) * DD;
        o[lane]      = run0 / denom;
        o[lane + 64] = run1 / denom;
        run0 = fmaf(a[s], w0[s], run0);   // position s contributes to positions > s
        run1 = fmaf(a[s], w1[s], run1);
    }
}

// Kernel 2: out[b,s,v] = SCALE * dot(ctx_n[b,s,:], emb[s,v,:]) / max(||emb[s,v,:]||, eps)
// 256 threads/block; each thread owns NV=4 vocab rows (v = v0 + k*256).
__global__ __launch_bounds__(256) void logits_kernel(
    const float* __restrict__ ctx_n,  // [S,B,D] (normalized)
    const float* __restrict__ emb,    // [S,V,D]
    float*       __restrict__ out)    // [B,S,V]
{
    const int s   = blockIdx.y;
    const int tid = threadIdx.x;

    __shared__ float4 ctx_s[BB * DD / 4];  // 512 float4 = 8 KB
    const float4* csrc = (const float4*)(ctx_n + (size_t)s * BB * DD);
    #pragma unroll
    for (int i = tid; i < BB * DD / 4; i += 256)
        ctx_s[i] = csrc[i];
    __syncthreads();

    const int v0 = blockIdx.x * (256 * NV) + tid;
    const float4* ebase = (const float4*)(emb + (size_t)s * VV * DD);

    // clamp OOB rows to a valid row for loads; stores are guarded
    int vidx[NV];
    #pragma unroll
    for (int k = 0; k < NV; ++k) {
        int v = v0 + k * 256;
        vidx[k] = (v < VV) ? v : (VV - 1);
    }

    float acc[NV][BB];
    float norm2[NV];
    #pragma unroll
    for (int k = 0; k < NV; ++k) {
        norm2[k] = 0.f;
        #pragma unroll
        for (int b = 0; b < BB; ++b) acc[k][b] = 0.f;
    }

    #pragma unroll 4
    for (int j = 0; j < DD / 4; ++j) {   // all 32 float4 chunks of the d-dim
        float4 ev[NV];
        #pragma unroll
        for (int k = 0; k < NV; ++k)
            ev[k] = ebase[(size_t)vidx[k] * (DD / 4) + j];

        #pragma unroll
        for (int k = 0; k < NV; ++k) {
            norm2[k] = fmaf(ev[k].x, ev[k].x, norm2[k]);
            norm2[k] = fmaf(ev[k].y, ev[k].y, norm2[k]);
            norm2[k] = fmaf(ev[k].z, ev[k].z, norm2[k]);
            norm2[k] = fmaf(ev[k].w, ev[k].w, norm2[k]);
        }

        #pragma unroll
        for (int b = 0; b < BB; ++b) {
            const float4 c = ctx_s[b * (DD / 4) + j];  // wave-uniform -> broadcast
            #pragma unroll
            for (int k = 0; k < NV; ++k) {
                acc[k][b] = fmaf(ev[k].x, c.x, acc[k][b]);
                acc[k][b] = fmaf(ev[k].y, c.y, acc[k][b]);
                acc[k][b] = fmaf(ev[k].z, c.z, acc[k][b]);
                acc[k][b] = fmaf(ev[k].w, c.w, acc[k][b]);
            }
        }
    }

    #pragma unroll
    for (int k = 0; k < NV; ++k) {
        const int v = v0 + k * 256;
        if (v >= VV) continue;
        const float f = SCALE / fmaxf(sqrtf(norm2[k]), EPS);
        #pragma unroll
        for (int b = 0; b < BB; ++b)
            out[((size_t)b * SS + s) * VV + v] = acc[k][b] * f;
    }
}

extern "C" void kernel_launch(void* const* d_in, const int* in_sizes, int n_in,
                              void* d_out, int out_size, void* d_ws, size_t ws_size,
                              hipStream_t stream) {
    const int*   tokens  = (const int*)d_in[0];
    const float* scalars = (const float*)d_in[1];
    const float* wvecs   = (const float*)d_in[2];
    const float* emb     = (const float*)d_in[3];
    float*       out     = (float*)d_out;
    float*       ctx_n   = (float*)d_ws;   // needs S*B*D*4 = 393,216 bytes

    ctx_kernel<<<dim3(BB), dim3(64), 0, stream>>>(tokens, scalars, wvecs, ctx_n);

    dim3 grid((VV + 256 * NV - 1) / (256 * NV), SS);   // (16, 48)
    logits_kernel<<<grid, dim3(256), 0, stream>>>(ctx_n, emb, out);
}